// Round 5
// baseline (415.513 us; speedup 1.0000x reference)
//
#include <hip/hip_runtime.h>
#include <math.h>

#define T_LEN 1024
#define BATCH 1024
#define H 64
#define NB 2   // batches per block (R21: halved -> 2 blocks/CU, 2 waves/SIMD)

typedef __attribute__((ext_vector_type(8))) _Float16 f16x8;
typedef __attribute__((ext_vector_type(4))) float    f32x4;

#define L2E     1.44269504088896340736f
#define TWO_L2E 2.88539008177792681472f

__device__ __forceinline__ float fast_rcp(float x)   { return __builtin_amdgcn_rcpf(x); }
__device__ __forceinline__ float exp2f_fast(float x) { return __builtin_amdgcn_exp2f(x); }

// ===================== encoder =====================
// R20 post-mortem: VALUBusy 200cyc + MfmaUtil 135cyc of the 558cyc step;
// ~220cyc is unhidden latency (ds_read ~120, MFMA+trans chain, barrier
// skew) because occupancy was pinned at 1 wave/SIMD. Instruction count is
// near its floor (8 MFMA structural; epilogue already fma/exp2-minimal).
//
// R21: break the occupancy pin. NB 4->2, grid 256->512, launch_bounds
// (256,2): two INDEPENDENT blocks per CU -> 2 waves/SIMD. While one
// block's waves sit in barrier/ds_read/trans latency, the other's issue.
// Per-window issue doubles but the window steps BOTH blocks (same 256
// cells/CU/window). A-tile now holds 8 replicas of 2 batches; lane pairs
// (q, q+1) duplicate one cell (bat = q>>1) — redundant epilogue is free
// (per-lane anyway), numerics bitwise identical. Writers predicated to
// even q. LDS 8.8KB/block -> 2 blocks fit trivially; 52 VGPR -> 2 waves ok.
//
// Kept: R20 f16 h-exchange + mfma_f32_16x16x32_f16 (2 chained k-halves,
// 8 MFMA/step/wave); unit-chunk-major hbuf (A-read = 8 distinct b128
// addrs x 8-way broadcast, spans all 32 banks, conflict-free — measured 0);
// R17b/R19 exp2-domain merged-reciprocal fma-formed epilogue; R18 x
// batch-major + base-fmas per 4 steps off the serial chain.
__global__ __launch_bounds__(256, 2) void encoder_kernel(
    const float* __restrict__ x,      // [T, BATCH]
    const float* __restrict__ Wih_e,  // [256, 1]
    const float* __restrict__ Whh_e,  // [256, 64]
    const float* __restrict__ bih_e,  // [256]
    const float* __restrict__ bhh_e,  // [256]
    float* __restrict__ h_enc)        // [BATCH, 64]
{
  // [parity][jchunk(8)][bat(NB)][8] : unit u -> jchunk u>>3, slot u&7
  __shared__ __align__(16) _Float16 hbuf[2][8][NB][8];    // 512 B
  __shared__ __align__(16) float x_lds[NB][T_LEN + 8];    // 8.06 KB

  const int tid  = threadIdx.x;
  const int lane = tid & 63;
  const int wv   = tid >> 6;        // unit-group (0..3)
  const int q    = lane >> 4;       // k-chunk for A/B fragments
  const int l15  = lane & 15;
  const int b0   = blockIdx.x * NB;
  const int u    = wv * 16 + l15;   // this lane's hidden unit
  const int bat  = q >> 1;          // lane's cell batch (A rows 0-7=b0, 8-15=b1)
  const bool writer = ((q & 1) == 0);  // dedupe the 2-lane cell replicas

  // ---- persistent f16 weight fragments: 4 gates x 2 k-halves, 32 VGPRs ----
  f16x8 Bh[4][2];
  float wih_s[4], bias_s[4], kS[4];
  const float mg[4] = {-L2E, -L2E, TWO_L2E, -L2E};  // exp2-domain gate scales
  for (int g = 0; g < 4; ++g) {
    const int n = g * 64 + u;       // gate row
#pragma unroll
    for (int hf = 0; hf < 2; ++hf) {
      f16x8 bv;
#pragma unroll
      for (int j = 0; j < 8; ++j)
        bv[j] = (_Float16)Whh_e[n * H + hf * 32 + q * 8 + j];
      Bh[g][hf] = bv;
    }
    wih_s[g]  = Wih_e[n] * mg[g];
    bias_s[g] = (bih_e[n] + bhh_e[n]) * mg[g];
    kS[g]     = mg[g];
  }

  // A-fragment read base: A row l15 = batch l15>>3, k-chunk q -> jchunk q
  // (k-half 0) and jchunk 4+q (k-half 1, +64 f16).
  const _Float16* ar0[2] = { &hbuf[0][q][l15 >> 3][0], &hbuf[1][q][l15 >> 3][0] };
  // write target for parity P writes into buffer 1-P
  _Float16* wrp[2] = { &hbuf[1][u >> 3][bat][u & 7], &hbuf[0][u >> 3][bat][u & 7] };

  // ---- one-time staging: x transposed to [bat][t] + zero h-state ----
  for (int t = tid; t < T_LEN; t += 256) {
    const float2 xv = *(const float2*)&x[t * BATCH + b0];
    x_lds[0][t] = xv.x;
    x_lds[1][t] = xv.y;
  }
  for (int i = tid; i < 2 * 8 * NB * 8; i += 256)
    ((_Float16*)hbuf)[i] = (_Float16)0.0f;   // h=0
  __syncthreads();

  float cs = 0.0f;       // cs = 2*log2e * c
  float h_last = 0.0f;
  const f32x4 fzero = {0.0f, 0.0f, 0.0f, 0.0f};

#define ENC_STEP(P, BASE)                                                      \
  {                                                                            \
    const f16x8 A1 = *(const f16x8*)(ar0[P]);                                  \
    const f16x8 A2 = *(const f16x8*)(ar0[P] + 4 * NB * 8);                     \
    float arg[4];                                                              \
    _Pragma("unroll")                                                          \
    for (int g = 0; g < 4; ++g) {                                              \
      f32x4 D = __builtin_amdgcn_mfma_f32_16x16x32_f16(A1, Bh[g][0], fzero, 0, 0, 0); \
      D = __builtin_amdgcn_mfma_f32_16x16x32_f16(A2, Bh[g][1], D, 0, 0, 0);    \
      arg[g] = fmaf(D[0], kS[g], (BASE)[g]);                                   \
    }                                                                          \
    /* merged-reciprocal cell update, all-exp2 domain, fma-formed */           \
    const float p  = exp2f_fast(arg[0]);      /* e^-G0  (i gate) */            \
    const float pf = exp2f_fast(arg[1]);      /* e^-G1  (f gate) */            \
    const float r  = exp2f_fast(arg[2]);      /* e^{2 G2} (g gate) */          \
    const float uo = exp2f_fast(arg[3]);      /* e^-G3  (o gate) */            \
    const float fv  = fast_rcp(1.0f + pf);                                     \
    const float r1  = r + 1.0f;                                                \
    const float den = fmaf(p, r1, r1);            /* (1+p)(1+r) */             \
    const float rm  = fmaf(r, TWO_L2E, -TWO_L2E); /* 2L2E*(r-1) */             \
    cs = fmaf(fv, cs, rm * fast_rcp(den));                                     \
    const float s  = exp2f_fast(cs);          /* e^{2c} */                     \
    const float s1 = s + 1.0f;                                                 \
    const float den2 = fmaf(uo, s1, s1);          /* (1+uo)(1+s) */            \
    const float h  = (s - 1.0f) * fast_rcp(den2); /* o*tanh(c) */              \
    if (writer) *wrp[P] = (_Float16)h;                                         \
    h_last = h;                                                                \
    __syncthreads();                                                           \
  }

  for (int t = 0; t < T_LEN; t += 4) {
    // one b128 x-read + 16 fma per 4 steps, all off the serial chain
    const float4 xf = *(const float4*)&x_lds[bat][t];
    float base[4][4];
#pragma unroll
    for (int ts = 0; ts < 4; ++ts) {
      const float xv = ((const float*)&xf)[ts];
#pragma unroll
      for (int g = 0; g < 4; ++g)
        base[ts][g] = fmaf(xv, wih_s[g], bias_s[g]);
    }
    ENC_STEP(0, base[0])
    ENC_STEP(1, base[1])
    ENC_STEP(0, base[2])
    ENC_STEP(1, base[3])
  }
#undef ENC_STEP

  // output the full-f32 final h (pre-f16-rounding): strictly closer to ref
  if (writer) h_enc[(b0 + bat) * H + u] = h_last;
}

// ===================== decoder =====================
// Wide form (validated ~117-119us, R19/R20): one lane per batch, 16 waves,
// grid 16, latency floor = two dependent trans rounds per step on the
// h->c->h chain. Gate constants pre-scaled by -L2E / +2L2E; c kept in 2L2E
// domain; h recurrence explicit. UNTOUCHED.
__global__ __launch_bounds__(64) void decoder_kernel(
    const float* __restrict__ h_enc,  // [BATCH, 64]
    const float* __restrict__ Wih,    // [4, 64]
    const float* __restrict__ Whh,    // [4, 1]
    const float* __restrict__ bih,    // [4]
    const float* __restrict__ bhh,    // [4]
    float* __restrict__ out)          // [T, BATCH]
{
  const int b = blockIdx.x * blockDim.x + threadIdx.x;

  float a0 = bih[0] + bhh[0];
  float a1 = bih[1] + bhh[1];
  float a2 = bih[2] + bhh[2];
  float a3 = bih[3] + bhh[3];
#pragma unroll 8
  for (int k = 0; k < H; ++k) {
    const float hv = h_enc[b * H + k];
    a0 = fmaf(Wih[0 * H + k], hv, a0);
    a1 = fmaf(Wih[1 * H + k], hv, a1);
    a2 = fmaf(Wih[2 * H + k], hv, a2);
    a3 = fmaf(Wih[3 * H + k], hv, a3);
  }
  // exp2-domain constants: sigmoid gates scaled by -L2E, tanh gate +2*L2E
  const float wS0 = -L2E * Whh[0],     aS0 = -L2E * a0;      // i
  const float wS1 = -L2E * Whh[1],     aS1 = -L2E * a1;      // f
  const float wS2 = TWO_L2E * Whh[2],  aS2 = TWO_L2E * a2;   // g
  const float wS3 = -L2E * Whh[3],     aS3 = -L2E * a3;      // o

  float h = 0.0f, cs = 0.0f;   // cs = 2*log2e * c
  float* outp = out + b;
  for (int t = 0; t < T_LEN; t += 8) {
    float buf[8];
#pragma unroll
    for (int uu = 0; uu < 8; ++uu) {
      const float pi = exp2f_fast(fmaf(wS0, h, aS0));
      const float pf = exp2f_fast(fmaf(wS1, h, aS1));
      const float rg = exp2f_fast(fmaf(wS2, h, aS2));
      const float po = exp2f_fast(fmaf(wS3, h, aS3));
      const float iv = fast_rcp(1.0f + pi);
      const float fv = fast_rcp(1.0f + pf);
      const float ov = fast_rcp(1.0f + po);
      const float gm = fmaf(rg, TWO_L2E, -TWO_L2E);      // 2L2E*(rg-1)
      const float gt = gm * fast_rcp(rg + 1.0f);         // 2L2E*tanh(G2)
      cs = fmaf(fv, cs, iv * gt);
      const float s  = exp2f_fast(cs);                   // e^{2c}
      const float tc = fast_rcp(1.0f + s);
      h = fmaf(-2.0f * ov, tc, ov);                      // ov * tanh(c)
      buf[uu] = h;
    }
#pragma unroll
    for (int uu = 0; uu < 8; ++uu)
      outp[(t + uu) * BATCH] = buf[uu];
  }
}

extern "C" void kernel_launch(void* const* d_in, const int* in_sizes, int n_in,
                              void* d_out, int out_size, void* d_ws, size_t ws_size,
                              hipStream_t stream) {
  const float* x     = (const float*)d_in[0];
  const float* Wih_e = (const float*)d_in[1];
  const float* Whh_e = (const float*)d_in[2];
  const float* bih_e = (const float*)d_in[3];
  const float* bhh_e = (const float*)d_in[4];
  const float* Wih_d = (const float*)d_in[5];
  const float* Whh_d = (const float*)d_in[6];
  const float* bih_d = (const float*)d_in[7];
  const float* bhh_d = (const float*)d_in[8];
  float* out = (float*)d_out;

  float* h_enc = (float*)d_ws;  // 1024*64*4 = 256 KB scratch

  encoder_kernel<<<BATCH / NB, 256, 0, stream>>>(x, Wih_e, Whh_e, bih_e, bhh_e, h_enc);
  decoder_kernel<<<BATCH / 64, 64, 0, stream>>>(h_enc, Wih_d, Whh_d, bih_d, bhh_d, out);
}

// Round 6
// 356.503 us; speedup vs baseline: 1.1655x; 1.1655x over previous
//
#include <hip/hip_runtime.h>
#include <math.h>

#define T_LEN 1024
#define BATCH 1024
#define H 64
#define NB 4   // batches per block (R22: reverted to R20's validated value)

typedef __attribute__((ext_vector_type(8))) _Float16 f16x8;
typedef __attribute__((ext_vector_type(4))) float    f32x4;

#define L2E     1.44269504088896340736f
#define TWO_L2E 2.88539008177792681472f

__device__ __forceinline__ float fast_rcp(float x)   { return __builtin_amdgcn_rcpf(x); }
__device__ __forceinline__ float exp2f_fast(float x) { return __builtin_amdgcn_exp2f(x); }

// ===================== encoder =====================
// R21 POST-MORTEM (regression 238->310us, reverted): NB=2 / 2 blocks/CU
// doubled occupancy exactly as predicted (11.5->21.2%) but the A-tile
// replication doubled per-CELL issue (VALU 52%=2x200cyc, Mfma 38%=2x135cyc
// -- counters matched the build, not the hope). Doubling ~335cyc of issue
// to hide ~220cyc of latency is a guaranteed loss. Structural conclusion:
// >1 wave/SIMD requires duplication (measured loss) or K-split reduction
// (extra barrier on a barrier-bound loop). R20's decomposition is final:
// grid 256 x 256thr, 1 block/CU, NB=4, lane owns one (batch,unit) cell.
//
// R20 (kept): f16 h-exchange + mfma_f32_16x16x32_f16, unit-chunk-major
// hbuf (conflict-free, measured 0), ~558cyc/step = 200 VALU + 135 MFMA
// + ~220 unhidden latency.
// R17b/R19 (kept): exp2-domain merged-reciprocal fma-formed epilogue,
// c in 2*log2e domain. R18 (kept): x batch-major, base-fmas per 4 steps
// off the serial chain.
//
// R22: two-phase MFMA issue order. The per-gate k-half pair was written
// chained back-to-back (M2 accumulates onto M1's result immediately);
// if emitted adjacently each gate stalls on its own accumulator. Phase 1
// issues all 4 gates' k-half-0 MFMAs, phase 2 all 4 accumulating k-half-1
// MFMAs: every dependent MFMA gets ~3 intervening slots (~60cyc) to
// retire. Zero added instructions; tests the scheduling theory directly.
__global__ __launch_bounds__(256, 1) void encoder_kernel(
    const float* __restrict__ x,      // [T, BATCH]
    const float* __restrict__ Wih_e,  // [256, 1]
    const float* __restrict__ Whh_e,  // [256, 64]
    const float* __restrict__ bih_e,  // [256]
    const float* __restrict__ bhh_e,  // [256]
    float* __restrict__ h_enc)        // [BATCH, 64]
{
  // [parity][jchunk(8)][bat(NB)][8] : unit u -> jchunk u>>3, slot u&7
  __shared__ __align__(16) _Float16 hbuf[2][8][NB][8];    // 1 KB
  __shared__ __align__(16) float x_lds[NB][T_LEN + 4];    // 16.06 KB

  const int tid  = threadIdx.x;
  const int lane = tid & 63;
  const int wv   = tid >> 6;        // unit-group (0..3)
  const int q    = lane >> 4;       // k-chunk for A/B fragments; cell batch
  const int l15  = lane & 15;
  const int b0   = blockIdx.x * NB;
  const int u    = wv * 16 + l15;   // this lane's hidden unit
  const int bat  = q;               // this lane's cell batch

  // ---- persistent f16 weight fragments: 4 gates x 2 k-halves, 32 VGPRs ----
  f16x8 Bh[4][2];
  float wih_s[4], bias_s[4], kS[4];
  const float mg[4] = {-L2E, -L2E, TWO_L2E, -L2E};  // exp2-domain gate scales
  for (int g = 0; g < 4; ++g) {
    const int n = g * 64 + u;       // gate row
#pragma unroll
    for (int hf = 0; hf < 2; ++hf) {
      f16x8 bv;
#pragma unroll
      for (int j = 0; j < 8; ++j)
        bv[j] = (_Float16)Whh_e[n * H + hf * 32 + q * 8 + j];
      Bh[g][hf] = bv;
    }
    wih_s[g]  = Wih_e[n] * mg[g];
    bias_s[g] = (bih_e[n] + bhh_e[n]) * mg[g];
    kS[g]     = mg[g];
  }

  // A-fragment read base (row = l15 -> batch l15>>2), k-chunk q; second
  // k-half sits +128 f16 further ([jchunk] stride 32 f16, +4 chunks).
  const _Float16* ar0[2] = { &hbuf[0][q][l15 >> 2][0], &hbuf[1][q][l15 >> 2][0] };
  // write target for parity P writes into buffer 1-P
  _Float16* wrp[2] = { &hbuf[1][u >> 3][bat][u & 7], &hbuf[0][u >> 3][bat][u & 7] };

  // ---- one-time staging: x transposed to [bat][t] + zero h-state ----
  for (int t = tid; t < T_LEN; t += 256) {
    const float4 xv = *(const float4*)&x[t * BATCH + b0];
    x_lds[0][t] = xv.x;
    x_lds[1][t] = xv.y;
    x_lds[2][t] = xv.z;
    x_lds[3][t] = xv.w;
  }
  for (int i = tid; i < 2 * 8 * NB * 8; i += 256)
    ((_Float16*)hbuf)[i] = (_Float16)0.0f;   // h=0
  __syncthreads();

  float cs = 0.0f;       // cs = 2*log2e * c
  float h_last = 0.0f;
  const f32x4 fzero = {0.0f, 0.0f, 0.0f, 0.0f};

#define ENC_STEP(P, BASE)                                                      \
  {                                                                            \
    const f16x8 A1 = *(const f16x8*)(ar0[P]);                                  \
    const f16x8 A2 = *(const f16x8*)(ar0[P] + 128);                            \
    f32x4 D[4];                                                                \
    /* phase 1: all gates' k-half-0 (independent, fill the MFMA pipe) */       \
    _Pragma("unroll")                                                          \
    for (int g = 0; g < 4; ++g)                                                \
      D[g] = __builtin_amdgcn_mfma_f32_16x16x32_f16(A1, Bh[g][0], fzero, 0, 0, 0); \
    /* phase 2: accumulating k-half-1 — each dep has ~3 slots to retire */     \
    _Pragma("unroll")                                                          \
    for (int g = 0; g < 4; ++g)                                                \
      D[g] = __builtin_amdgcn_mfma_f32_16x16x32_f16(A2, Bh[g][1], D[g], 0, 0, 0); \
    float arg[4];                                                              \
    _Pragma("unroll")                                                          \
    for (int g = 0; g < 4; ++g)                                                \
      arg[g] = fmaf(D[g][0], kS[g], (BASE)[g]);                                \
    /* merged-reciprocal cell update, all-exp2 domain, fma-formed */           \
    const float p  = exp2f_fast(arg[0]);      /* e^-G0  (i gate) */            \
    const float pf = exp2f_fast(arg[1]);      /* e^-G1  (f gate) */            \
    const float r  = exp2f_fast(arg[2]);      /* e^{2 G2} (g gate) */          \
    const float uo = exp2f_fast(arg[3]);      /* e^-G3  (o gate) */            \
    const float fv  = fast_rcp(1.0f + pf);                                     \
    const float r1  = r + 1.0f;                                                \
    const float den = fmaf(p, r1, r1);            /* (1+p)(1+r) */             \
    const float rm  = fmaf(r, TWO_L2E, -TWO_L2E); /* 2L2E*(r-1) */             \
    cs = fmaf(fv, cs, rm * fast_rcp(den));                                     \
    const float s  = exp2f_fast(cs);          /* e^{2c} */                     \
    const float s1 = s + 1.0f;                                                 \
    const float den2 = fmaf(uo, s1, s1);          /* (1+uo)(1+s) */            \
    const float h  = (s - 1.0f) * fast_rcp(den2); /* o*tanh(c) */              \
    *wrp[P] = (_Float16)h;                                                     \
    h_last = h;                                                                \
    __syncthreads();                                                           \
  }

  for (int t = 0; t < T_LEN; t += 4) {
    // one b128 x-read + 16 fma per 4 steps, all off the serial chain
    const float4 xf = *(const float4*)&x_lds[bat][t];
    float base[4][4];
#pragma unroll
    for (int ts = 0; ts < 4; ++ts) {
      const float xv = ((const float*)&xf)[ts];
#pragma unroll
      for (int g = 0; g < 4; ++g)
        base[ts][g] = fmaf(xv, wih_s[g], bias_s[g]);
    }
    ENC_STEP(0, base[0])
    ENC_STEP(1, base[1])
    ENC_STEP(0, base[2])
    ENC_STEP(1, base[3])
  }
#undef ENC_STEP

  // output the full-f32 final h (pre-f16-rounding): strictly closer to ref
  h_enc[(b0 + bat) * H + u] = h_last;
}

// ===================== decoder =====================
// Wide form (validated ~117-119us, R19/R20): one lane per batch, 16 waves,
// grid 16, latency floor = two dependent trans rounds per step on the
// h->c->h chain. Gate constants pre-scaled by -L2E / +2L2E; c kept in 2L2E
// domain; h recurrence explicit. UNTOUCHED (absmax is decoder-dominated;
// R17 showed decoder refactors regress unpredictably — do not perturb).
__global__ __launch_bounds__(64) void decoder_kernel(
    const float* __restrict__ h_enc,  // [BATCH, 64]
    const float* __restrict__ Wih,    // [4, 64]
    const float* __restrict__ Whh,    // [4, 1]
    const float* __restrict__ bih,    // [4]
    const float* __restrict__ bhh,    // [4]
    float* __restrict__ out)          // [T, BATCH]
{
  const int b = blockIdx.x * blockDim.x + threadIdx.x;

  float a0 = bih[0] + bhh[0];
  float a1 = bih[1] + bhh[1];
  float a2 = bih[2] + bhh[2];
  float a3 = bih[3] + bhh[3];
#pragma unroll 8
  for (int k = 0; k < H; ++k) {
    const float hv = h_enc[b * H + k];
    a0 = fmaf(Wih[0 * H + k], hv, a0);
    a1 = fmaf(Wih[1 * H + k], hv, a1);
    a2 = fmaf(Wih[2 * H + k], hv, a2);
    a3 = fmaf(Wih[3 * H + k], hv, a3);
  }
  // exp2-domain constants: sigmoid gates scaled by -L2E, tanh gate +2*L2E
  const float wS0 = -L2E * Whh[0],     aS0 = -L2E * a0;      // i
  const float wS1 = -L2E * Whh[1],     aS1 = -L2E * a1;      // f
  const float wS2 = TWO_L2E * Whh[2],  aS2 = TWO_L2E * a2;   // g
  const float wS3 = -L2E * Whh[3],     aS3 = -L2E * a3;      // o

  float h = 0.0f, cs = 0.0f;   // cs = 2*log2e * c
  float* outp = out + b;
  for (int t = 0; t < T_LEN; t += 8) {
    float buf[8];
#pragma unroll
    for (int uu = 0; uu < 8; ++uu) {
      const float pi = exp2f_fast(fmaf(wS0, h, aS0));
      const float pf = exp2f_fast(fmaf(wS1, h, aS1));
      const float rg = exp2f_fast(fmaf(wS2, h, aS2));
      const float po = exp2f_fast(fmaf(wS3, h, aS3));
      const float iv = fast_rcp(1.0f + pi);
      const float fv = fast_rcp(1.0f + pf);
      const float ov = fast_rcp(1.0f + po);
      const float gm = fmaf(rg, TWO_L2E, -TWO_L2E);      // 2L2E*(rg-1)
      const float gt = gm * fast_rcp(rg + 1.0f);         // 2L2E*tanh(G2)
      cs = fmaf(fv, cs, iv * gt);
      const float s  = exp2f_fast(cs);                   // e^{2c}
      const float tc = fast_rcp(1.0f + s);
      h = fmaf(-2.0f * ov, tc, ov);                      // ov * tanh(c)
      buf[uu] = h;
    }
#pragma unroll
    for (int uu = 0; uu < 8; ++uu)
      outp[(t + uu) * BATCH] = buf[uu];
  }
}

extern "C" void kernel_launch(void* const* d_in, const int* in_sizes, int n_in,
                              void* d_out, int out_size, void* d_ws, size_t ws_size,
                              hipStream_t stream) {
  const float* x     = (const float*)d_in[0];
  const float* Wih_e = (const float*)d_in[1];
  const float* Whh_e = (const float*)d_in[2];
  const float* bih_e = (const float*)d_in[3];
  const float* bhh_e = (const float*)d_in[4];
  const float* Wih_d = (const float*)d_in[5];
  const float* Whh_d = (const float*)d_in[6];
  const float* bih_d = (const float*)d_in[7];
  const float* bhh_d = (const float*)d_in[8];
  float* out = (float*)d_out;

  float* h_enc = (float*)d_ws;  // 1024*64*4 = 256 KB scratch

  encoder_kernel<<<BATCH / NB, 256, 0, stream>>>(x, Wih_e, Whh_e, bih_e, bhh_e, h_enc);
  decoder_kernel<<<BATCH / 64, 64, 0, stream>>>(h_enc, Wih_d, Whh_d, bih_d, bhh_d, out);
}